// Round 1
// baseline (2482.626 us; speedup 1.0000x reference)
//
#include <hip/hip_runtime.h>
#include <hip/hip_bf16.h>
#include <math.h>

#define B_SZ    2
#define LSEQ    2048
#define DMODEL  1024
#define DINNER  2048
#define DSTATE  16
#define DCONV   4
#define DTRANK  64

static __device__ __forceinline__ float sigmoidf_(float x) {
    return 1.0f / (1.0f + __expf(-x));
}

// ----------------------------------------------------------------------------
// Generic f32 tiled GEMM: C[M,N] = A[M,K] @ B[K,N], row-major with strides.
// epi==1: C = softplus(C + bias[col])
// ----------------------------------------------------------------------------
#define BM  64
#define BN  64
#define BKK 16

__global__ __launch_bounds__(256) void gemm_f32(
    const float* __restrict__ A, int lda,
    const float* __restrict__ B, int ldb,
    float* __restrict__ C, int ldc,
    int M, int N, int K, int epi, const float* __restrict__ bias)
{
    __shared__ float As[BKK][BM];
    __shared__ float Bs[BKK][BN];

    const int tid = threadIdx.x;
    const int bm = blockIdx.y * BM;
    const int bn = blockIdx.x * BN;
    const int tx = tid & 15;        // output col group
    const int ty = tid >> 4;        // output row group
    const int arow = tid >> 2;      // 0..63
    const int acol = (tid & 3) << 2;
    const int brow = tid >> 4;      // 0..15
    const int bcol = (tid & 15) << 2;

    float acc[4][4];
    #pragma unroll
    for (int i = 0; i < 4; i++)
        #pragma unroll
        for (int j = 0; j < 4; j++) acc[i][j] = 0.f;

    for (int k0 = 0; k0 < K; k0 += BKK) {
        float4 av = make_float4(0.f, 0.f, 0.f, 0.f);
        {
            const int gr = bm + arow;
            const int gc = k0 + acol;
            if (gr < M && gc + 4 <= K)
                av = *reinterpret_cast<const float4*>(A + (size_t)gr * lda + gc);
        }
        float4 bv = make_float4(0.f, 0.f, 0.f, 0.f);
        {
            const int gr = k0 + brow;
            const int gc = bn + bcol;
            if (gr < K && gc + 4 <= N)
                bv = *reinterpret_cast<const float4*>(B + (size_t)gr * ldb + gc);
        }
        As[acol + 0][arow] = av.x;
        As[acol + 1][arow] = av.y;
        As[acol + 2][arow] = av.z;
        As[acol + 3][arow] = av.w;
        *reinterpret_cast<float4*>(&Bs[brow][bcol]) = bv;
        __syncthreads();

        #pragma unroll
        for (int k = 0; k < BKK; k++) {
            float a[4], b[4];
            #pragma unroll
            for (int i = 0; i < 4; i++) a[i] = As[k][(ty << 2) + i];
            #pragma unroll
            for (int j = 0; j < 4; j++) b[j] = Bs[k][(tx << 2) + j];
            #pragma unroll
            for (int i = 0; i < 4; i++)
                #pragma unroll
                for (int j = 0; j < 4; j++)
                    acc[i][j] = fmaf(a[i], b[j], acc[i][j]);
        }
        __syncthreads();
    }

    #pragma unroll
    for (int i = 0; i < 4; i++) {
        const int row = bm + (ty << 2) + i;
        if (row >= M) continue;
        #pragma unroll
        for (int j = 0; j < 4; j++) {
            const int col = bn + (tx << 2) + j;
            if (col >= N) continue;
            float v = acc[i][j];
            if (epi == 1) {
                v += bias[col];
                v = (v > 20.f) ? v : log1pf(__expf(v));   // softplus
            }
            C[(size_t)row * ldc + col] = v;
        }
    }
}

// ----------------------------------------------------------------------------
// Causal depthwise conv (width 4, left pad 3) + bias + SiLU.
// xz is [B*L, 2*DINNER]; the xs half is columns [0, DINNER). Output u [B*L, DINNER].
// ----------------------------------------------------------------------------
__global__ __launch_bounds__(256) void conv_silu(
    const float* __restrict__ xz, const float* __restrict__ conv_w,
    const float* __restrict__ conv_b, float* __restrict__ u)
{
    const int idx = blockIdx.x * 256 + threadIdx.x;   // over B*L*DINNER
    if (idx >= B_SZ * LSEQ * DINNER) return;
    const int d  = idx & (DINNER - 1);
    const int bl = idx >> 11;                          // b*L + l
    const int l  = bl & (LSEQ - 1);

    float acc = conv_b[d];
    #pragma unroll
    for (int k = 0; k < DCONV; k++) {
        const int l2 = l - (DCONV - 1) + k;
        if (l2 >= 0) {
            acc = fmaf(xz[(size_t)(bl - (DCONV - 1) + k) * (2 * DINNER) + d],
                       conv_w[d * DCONV + k], acc);
        }
    }
    u[idx] = acc * sigmoidf_(acc);
}

// ----------------------------------------------------------------------------
// Selective scan: one thread per (b, d) channel; 16 diagonal states.
// dy holds delta on input; overwritten in place with gated y.
// Gate: y = (ys + u*D[d]) * silu(res);  res = xz[:, DINNER + d].
// ----------------------------------------------------------------------------
__global__ __launch_bounds__(256) void scan_kernel(
    float* __restrict__ dy, const float* __restrict__ u,
    const float* __restrict__ xdbl, const float* __restrict__ xz,
    const float* __restrict__ A_log, const float* __restrict__ Dp)
{
    const int idx = blockIdx.x * 256 + threadIdx.x;   // b*DINNER + d
    if (idx >= B_SZ * DINNER) return;
    const int d = idx & (DINNER - 1);
    const int b = idx >> 11;

    float Arow[DSTATE];
    #pragma unroll
    for (int n = 0; n < DSTATE; n++) Arow[n] = -__expf(A_log[d * DSTATE + n]);
    const float Dd = Dp[d];

    float h[DSTATE];
    #pragma unroll
    for (int n = 0; n < DSTATE; n++) h[n] = 0.f;

    const size_t baseRow = (size_t)b * LSEQ;
    for (int l = 0; l < LSEQ; ++l) {
        const size_t r = baseRow + l;
        const float dv = dy[r * DINNER + d];
        const float uv = u[r * DINNER + d];

        const float4* bp = reinterpret_cast<const float4*>(xdbl + r * 96 + DTRANK);
        float Bv[DSTATE], Cv[DSTATE];
        {
            float4 t;
            t = bp[0]; Bv[0]=t.x; Bv[1]=t.y; Bv[2]=t.z; Bv[3]=t.w;
            t = bp[1]; Bv[4]=t.x; Bv[5]=t.y; Bv[6]=t.z; Bv[7]=t.w;
            t = bp[2]; Bv[8]=t.x; Bv[9]=t.y; Bv[10]=t.z; Bv[11]=t.w;
            t = bp[3]; Bv[12]=t.x; Bv[13]=t.y; Bv[14]=t.z; Bv[15]=t.w;
            t = bp[4]; Cv[0]=t.x; Cv[1]=t.y; Cv[2]=t.z; Cv[3]=t.w;
            t = bp[5]; Cv[4]=t.x; Cv[5]=t.y; Cv[6]=t.z; Cv[7]=t.w;
            t = bp[6]; Cv[8]=t.x; Cv[9]=t.y; Cv[10]=t.z; Cv[11]=t.w;
            t = bp[7]; Cv[12]=t.x; Cv[13]=t.y; Cv[14]=t.z; Cv[15]=t.w;
        }

        const float du = dv * uv;
        float yv = 0.f;
        #pragma unroll
        for (int n = 0; n < DSTATE; n++) {
            const float dA = __expf(dv * Arow[n]);
            h[n] = fmaf(dA, h[n], du * Bv[n]);
            yv = fmaf(h[n], Cv[n], yv);
        }
        yv = fmaf(uv, Dd, yv);

        const float rv = xz[r * (2 * DINNER) + DINNER + d];
        dy[r * DINNER + d] = yv * (rv * sigmoidf_(rv));
    }
}

// ----------------------------------------------------------------------------
extern "C" void kernel_launch(void* const* d_in, const int* in_sizes, int n_in,
                              void* d_out, int out_size, void* d_ws, size_t ws_size,
                              hipStream_t stream) {
    const float* x      = (const float*)d_in[0];
    const float* W_in   = (const float*)d_in[1];
    const float* conv_w = (const float*)d_in[2];
    const float* conv_b = (const float*)d_in[3];
    const float* W_x    = (const float*)d_in[4];
    const float* W_dt   = (const float*)d_in[5];
    const float* b_dt   = (const float*)d_in[6];
    const float* A_log  = (const float*)d_in[7];
    const float* Dp     = (const float*)d_in[8];
    const float* W_out  = (const float*)d_in[9];
    float* out = (float*)d_out;

    float* ws   = (float*)d_ws;
    float* xz   = ws;                                  // [4096, 4096]
    float* u    = xz   + (size_t)4096 * 4096;          // [4096, 2048]
    float* xdbl = u    + (size_t)4096 * 2048;          // [4096, 96]
    float* dy   = xdbl + (size_t)4096 * 96;            // [4096, 2048] delta -> y

    const int M = B_SZ * LSEQ;   // 4096
    dim3 blk(256);

    // 1) xz = x @ W_in                      [4096,1024]x[1024,4096]
    gemm_f32<<<dim3((2 * DINNER) / BN, M / BM), blk, 0, stream>>>(
        x, DMODEL, W_in, 2 * DINNER, xz, 2 * DINNER,
        M, 2 * DINNER, DMODEL, 0, nullptr);

    // 2) u = silu(causal_conv(xs) + conv_b)
    conv_silu<<<dim3((M * DINNER) / 256), blk, 0, stream>>>(xz, conv_w, conv_b, u);

    // 3) xdbl = u @ W_x                     [4096,2048]x[2048,96]
    gemm_f32<<<dim3((96 + BN - 1) / BN, M / BM), blk, 0, stream>>>(
        u, DINNER, W_x, 96, xdbl, 96,
        M, 96, DINNER, 0, nullptr);

    // 4) dy = softplus(xdbl[:, :64] @ W_dt + b_dt)   [4096,64]x[64,2048]
    gemm_f32<<<dim3(DINNER / BN, M / BM), blk, 0, stream>>>(
        xdbl, 96, W_dt, DINNER, dy, DINNER,
        M, DINNER, DTRANK, 1, b_dt);

    // 5) selective scan + D skip + gate (in place into dy)
    scan_kernel<<<dim3((B_SZ * DINNER) / 256), blk, 0, stream>>>(
        dy, u, xdbl, xz, A_log, Dp);

    // 6) out = dy @ W_out                   [4096,2048]x[2048,1024]
    gemm_f32<<<dim3(DMODEL / BN, M / BM), blk, 0, stream>>>(
        dy, DINNER, W_out, DMODEL, out, DMODEL,
        M, DMODEL, DINNER, 0, nullptr);
}

// Round 3
// 1112.404 us; speedup vs baseline: 2.2318x; 2.2318x over previous
//
#include <hip/hip_runtime.h>
#include <hip/hip_bf16.h>
#include <math.h>

#define B_SZ    2
#define LSEQ    2048
#define DMODEL  1024
#define DINNER  2048
#define DSTATE  16
#define DCONV   4
#define DTRANK  64

#define NCHUNK  64
#define CLEN    (LSEQ / NCHUNK)   // 32

static __device__ __forceinline__ float sigmoidf_(float x) {
    return 1.0f / (1.0f + __expf(-x));
}

// ----------------------------------------------------------------------------
// Generic f32 tiled GEMM: C[M,N] = A[M,K] @ B[K,N], row-major with strides.
// epi==1: C = softplus(C + bias[col])
// ----------------------------------------------------------------------------
#define BM  64
#define BN  64
#define BKK 16

__global__ __launch_bounds__(256) void gemm_f32(
    const float* __restrict__ A, int lda,
    const float* __restrict__ B, int ldb,
    float* __restrict__ C, int ldc,
    int M, int N, int K, int epi, const float* __restrict__ bias)
{
    __shared__ float As[BKK][BM];
    __shared__ float Bs[BKK][BN];

    const int tid = threadIdx.x;
    const int bm = blockIdx.y * BM;
    const int bn = blockIdx.x * BN;
    const int tx = tid & 15;        // output col group
    const int ty = tid >> 4;        // output row group
    const int arow = tid >> 2;      // 0..63
    const int acol = (tid & 3) << 2;
    const int brow = tid >> 4;      // 0..15
    const int bcol = (tid & 15) << 2;

    float acc[4][4];
    #pragma unroll
    for (int i = 0; i < 4; i++)
        #pragma unroll
        for (int j = 0; j < 4; j++) acc[i][j] = 0.f;

    for (int k0 = 0; k0 < K; k0 += BKK) {
        float4 av = make_float4(0.f, 0.f, 0.f, 0.f);
        {
            const int gr = bm + arow;
            const int gc = k0 + acol;
            if (gr < M && gc + 4 <= K)
                av = *reinterpret_cast<const float4*>(A + (size_t)gr * lda + gc);
        }
        float4 bv = make_float4(0.f, 0.f, 0.f, 0.f);
        {
            const int gr = k0 + brow;
            const int gc = bn + bcol;
            if (gr < K && gc + 4 <= N)
                bv = *reinterpret_cast<const float4*>(B + (size_t)gr * ldb + gc);
        }
        As[acol + 0][arow] = av.x;
        As[acol + 1][arow] = av.y;
        As[acol + 2][arow] = av.z;
        As[acol + 3][arow] = av.w;
        *reinterpret_cast<float4*>(&Bs[brow][bcol]) = bv;
        __syncthreads();

        #pragma unroll
        for (int k = 0; k < BKK; k++) {
            float a[4], b[4];
            #pragma unroll
            for (int i = 0; i < 4; i++) a[i] = As[k][(ty << 2) + i];
            #pragma unroll
            for (int j = 0; j < 4; j++) b[j] = Bs[k][(tx << 2) + j];
            #pragma unroll
            for (int i = 0; i < 4; i++)
                #pragma unroll
                for (int j = 0; j < 4; j++)
                    acc[i][j] = fmaf(a[i], b[j], acc[i][j]);
        }
        __syncthreads();
    }

    #pragma unroll
    for (int i = 0; i < 4; i++) {
        const int row = bm + (ty << 2) + i;
        if (row >= M) continue;
        #pragma unroll
        for (int j = 0; j < 4; j++) {
            const int col = bn + (tx << 2) + j;
            if (col >= N) continue;
            float v = acc[i][j];
            if (epi == 1) {
                v += bias[col];
                v = (v > 20.f) ? v : log1pf(__expf(v));   // softplus
            }
            C[(size_t)row * ldc + col] = v;
        }
    }
}

// ----------------------------------------------------------------------------
// Causal depthwise conv (width 4, left pad 3) + bias + SiLU.
// ----------------------------------------------------------------------------
__global__ __launch_bounds__(256) void conv_silu(
    const float* __restrict__ xz, const float* __restrict__ conv_w,
    const float* __restrict__ conv_b, float* __restrict__ u)
{
    const int idx = blockIdx.x * 256 + threadIdx.x;   // over B*L*DINNER
    if (idx >= B_SZ * LSEQ * DINNER) return;
    const int d  = idx & (DINNER - 1);
    const int bl = idx >> 11;                          // b*L + l
    const int l  = bl & (LSEQ - 1);

    float acc = conv_b[d];
    #pragma unroll
    for (int k = 0; k < DCONV; k++) {
        const int l2 = l - (DCONV - 1) + k;
        if (l2 >= 0) {
            acc = fmaf(xz[(size_t)(bl - (DCONV - 1) + k) * (2 * DINNER) + d],
                       conv_w[d * DCONV + k], acc);
        }
    }
    u[idx] = acc * sigmoidf_(acc);
}

// ----------------------------------------------------------------------------
// Chunk-parallel selective scan.
// Recurrence per (b,d,n): h[l] = exp(delta[l]*A_n)*h[l-1] + delta[l]*u[l]*B[l,n]
// Phase 1: per (b,d,chunk) scan from h=0 -> store h_end[16] and sum(delta).
// Phase 2: per (b,d,n) sequential combine over chunks (in place: hend -> hin).
// Phase 3: per (b,d,chunk) rescan with true hin; y = sum_n h*C + u*D; gate.
// ----------------------------------------------------------------------------
__global__ __launch_bounds__(256) void scan_phase1(
    const float* __restrict__ delta, const float* __restrict__ u,
    const float* __restrict__ xdbl, const float* __restrict__ A_log,
    float* __restrict__ hend, float* __restrict__ Sd)
{
    const int idx = blockIdx.x * 256 + threadIdx.x;   // ((b*NCHUNK+c)*DINNER+d)
    if (idx >= B_SZ * DINNER * NCHUNK) return;
    const int d = idx & (DINNER - 1);
    const int c = (idx >> 11) & (NCHUNK - 1);
    const int b = idx >> 17;

    float a[DSTATE];
    #pragma unroll
    for (int n = 0; n < DSTATE; n++) a[n] = -__expf(A_log[d * DSTATE + n]);

    float h[DSTATE];
    #pragma unroll
    for (int n = 0; n < DSTATE; n++) h[n] = 0.f;
    float sd = 0.f;

    const int l0 = b * LSEQ + c * CLEN;
    for (int i = 0; i < CLEN; ++i) {
        const size_t r = (size_t)(l0 + i);
        const float dv = delta[r * DINNER + d];
        const float uv = u[r * DINNER + d];
        sd += dv;
        const float4* bp = reinterpret_cast<const float4*>(xdbl + r * 96 + DTRANK);
        float Bv[DSTATE];
        {
            float4 t;
            t = bp[0]; Bv[0]=t.x; Bv[1]=t.y; Bv[2]=t.z;  Bv[3]=t.w;
            t = bp[1]; Bv[4]=t.x; Bv[5]=t.y; Bv[6]=t.z;  Bv[7]=t.w;
            t = bp[2]; Bv[8]=t.x; Bv[9]=t.y; Bv[10]=t.z; Bv[11]=t.w;
            t = bp[3]; Bv[12]=t.x; Bv[13]=t.y; Bv[14]=t.z; Bv[15]=t.w;
        }
        const float du = dv * uv;
        #pragma unroll
        for (int n = 0; n < DSTATE; n++)
            h[n] = fmaf(__expf(dv * a[n]), h[n], du * Bv[n]);
    }

    float* hp = hend + ((size_t)(b * DINNER + d) * NCHUNK + c) * DSTATE;
    #pragma unroll
    for (int n = 0; n < DSTATE; n += 4)
        *reinterpret_cast<float4*>(hp + n) = make_float4(h[n], h[n+1], h[n+2], h[n+3]);
    Sd[(size_t)(b * DINNER + d) * NCHUNK + c] = sd;
}

__global__ __launch_bounds__(256) void scan_phase2(
    float* __restrict__ hend, const float* __restrict__ Sd,
    const float* __restrict__ A_log)
{
    const int idx = blockIdx.x * 256 + threadIdx.x;   // ((b*DINNER+d)*16+n)
    if (idx >= B_SZ * DINNER * DSTATE) return;
    const int n = idx & (DSTATE - 1);
    const int d = (idx >> 4) & (DINNER - 1);
    const int b = idx >> 15;

    const float an = -__expf(A_log[d * DSTATE + n]);
    const size_t base = (size_t)(b * DINNER + d) * NCHUNK;
    float carry = 0.f;
    for (int c = 0; c < NCHUNK; ++c) {
        const float P = __expf(an * Sd[base + c]);
        const size_t off = (base + c) * DSTATE + n;
        const float tmp = hend[off];
        hend[off] = carry;                 // becomes h_in for chunk c
        carry = fmaf(P, carry, tmp);
    }
}

__global__ __launch_bounds__(256) void scan_phase3(
    float* __restrict__ dy /* delta in, gated y out */,
    const float* __restrict__ u, const float* __restrict__ xdbl,
    const float* __restrict__ xz, const float* __restrict__ A_log,
    const float* __restrict__ Dp, const float* __restrict__ hin)
{
    const int idx = blockIdx.x * 256 + threadIdx.x;   // ((b*NCHUNK+c)*DINNER+d)
    if (idx >= B_SZ * DINNER * NCHUNK) return;
    const int d = idx & (DINNER - 1);
    const int c = (idx >> 11) & (NCHUNK - 1);
    const int b = idx >> 17;

    float a[DSTATE];
    #pragma unroll
    for (int n = 0; n < DSTATE; n++) a[n] = -__expf(A_log[d * DSTATE + n]);
    const float Dd = Dp[d];

    float h[DSTATE];
    {
        const float* hp = hin + ((size_t)(b * DINNER + d) * NCHUNK + c) * DSTATE;
        #pragma unroll
        for (int n = 0; n < DSTATE; n += 4) {
            float4 t = *reinterpret_cast<const float4*>(hp + n);
            h[n] = t.x; h[n+1] = t.y; h[n+2] = t.z; h[n+3] = t.w;
        }
    }

    const int l0 = b * LSEQ + c * CLEN;
    for (int i = 0; i < CLEN; ++i) {
        const size_t r = (size_t)(l0 + i);
        const float dv = dy[r * DINNER + d];
        const float uv = u[r * DINNER + d];

        const float4* bp = reinterpret_cast<const float4*>(xdbl + r * 96 + DTRANK);
        float Bv[DSTATE], Cv[DSTATE];
        {
            float4 t;
            t = bp[0]; Bv[0]=t.x; Bv[1]=t.y; Bv[2]=t.z;  Bv[3]=t.w;
            t = bp[1]; Bv[4]=t.x; Bv[5]=t.y; Bv[6]=t.z;  Bv[7]=t.w;
            t = bp[2]; Bv[8]=t.x; Bv[9]=t.y; Bv[10]=t.z; Bv[11]=t.w;
            t = bp[3]; Bv[12]=t.x; Bv[13]=t.y; Bv[14]=t.z; Bv[15]=t.w;
            t = bp[4]; Cv[0]=t.x; Cv[1]=t.y; Cv[2]=t.z;  Cv[3]=t.w;
            t = bp[5]; Cv[4]=t.x; Cv[5]=t.y; Cv[6]=t.z;  Cv[7]=t.w;
            t = bp[6]; Cv[8]=t.x; Cv[9]=t.y; Cv[10]=t.z; Cv[11]=t.w;
            t = bp[7]; Cv[12]=t.x; Cv[13]=t.y; Cv[14]=t.z; Cv[15]=t.w;
        }

        const float du = dv * uv;
        float yv = 0.f;
        #pragma unroll
        for (int n = 0; n < DSTATE; n++) {
            h[n] = fmaf(__expf(dv * a[n]), h[n], du * Bv[n]);
            yv = fmaf(h[n], Cv[n], yv);
        }
        yv = fmaf(uv, Dd, yv);

        const float rv = xz[r * (2 * DINNER) + DINNER + d];
        dy[r * DINNER + d] = yv * (rv * sigmoidf_(rv));
    }
}

// ----------------------------------------------------------------------------
extern "C" void kernel_launch(void* const* d_in, const int* in_sizes, int n_in,
                              void* d_out, int out_size, void* d_ws, size_t ws_size,
                              hipStream_t stream) {
    const float* x      = (const float*)d_in[0];
    const float* W_in   = (const float*)d_in[1];
    const float* conv_w = (const float*)d_in[2];
    const float* conv_b = (const float*)d_in[3];
    const float* W_x    = (const float*)d_in[4];
    const float* W_dt   = (const float*)d_in[5];
    const float* b_dt   = (const float*)d_in[6];
    const float* A_log  = (const float*)d_in[7];
    const float* Dp     = (const float*)d_in[8];
    const float* W_out  = (const float*)d_in[9];
    float* out = (float*)d_out;

    float* ws   = (float*)d_ws;
    float* xz   = ws;                                   // [4096, 4096]
    float* u    = xz   + (size_t)4096 * 4096;           // [4096, 2048]
    float* xdbl = u    + (size_t)4096 * 2048;           // [4096, 96]
    float* dy   = xdbl + (size_t)4096 * 96;             // [4096, 2048] delta -> y
    float* hend = dy   + (size_t)4096 * 2048;           // [2,2048,NCHUNK,16]
    float* Sd   = hend + (size_t)B_SZ * DINNER * NCHUNK * DSTATE;  // [2,2048,NCHUNK]

    const int M = B_SZ * LSEQ;   // 4096
    dim3 blk(256);

    // 1) xz = x @ W_in                      [4096,1024]x[1024,4096]
    gemm_f32<<<dim3((2 * DINNER) / BN, M / BM), blk, 0, stream>>>(
        x, DMODEL, W_in, 2 * DINNER, xz, 2 * DINNER,
        M, 2 * DINNER, DMODEL, 0, nullptr);

    // 2) u = silu(causal_conv(xs) + conv_b)
    conv_silu<<<dim3((M * DINNER) / 256), blk, 0, stream>>>(xz, conv_w, conv_b, u);

    // 3) xdbl = u @ W_x                     [4096,2048]x[2048,96]
    gemm_f32<<<dim3((96 + BN - 1) / BN, M / BM), blk, 0, stream>>>(
        u, DINNER, W_x, 96, xdbl, 96,
        M, 96, DINNER, 0, nullptr);

    // 4) dy = softplus(xdbl[:, :64] @ W_dt + b_dt)   [4096,64]x[64,2048]
    gemm_f32<<<dim3(DINNER / BN, M / BM), blk, 0, stream>>>(
        xdbl, 96, W_dt, DINNER, dy, DINNER,
        M, DINNER, DTRANK, 1, b_dt);

    // 5) chunk-parallel selective scan + D skip + gate (in place into dy)
    scan_phase1<<<dim3((B_SZ * DINNER * NCHUNK) / 256), blk, 0, stream>>>(
        dy, u, xdbl, A_log, hend, Sd);
    scan_phase2<<<dim3((B_SZ * DINNER * DSTATE) / 256), blk, 0, stream>>>(
        hend, Sd, A_log);
    scan_phase3<<<dim3((B_SZ * DINNER * NCHUNK) / 256), blk, 0, stream>>>(
        dy, u, xdbl, xz, A_log, Dp, hend);

    // 6) out = dy @ W_out                   [4096,2048]x[2048,1024]
    gemm_f32<<<dim3(DMODEL / BN, M / BM), blk, 0, stream>>>(
        dy, DINNER, W_out, DMODEL, out, DMODEL,
        M, DMODEL, DINNER, 0, nullptr);
}

// Round 4
// 524.443 us; speedup vs baseline: 4.7338x; 2.1211x over previous
//
#include <hip/hip_runtime.h>
#include <hip/hip_bf16.h>
#include <math.h>

#define B_SZ    2
#define LSEQ    2048
#define DMODEL  1024
#define DINNER  2048
#define DSTATE  16
#define DCONV   4
#define DTRANK  64

#define NCHUNK  64
#define CLEN    (LSEQ / NCHUNK)   // 32

typedef unsigned short u16;
typedef __bf16 bf16x8 __attribute__((ext_vector_type(8)));
typedef float  f32x4  __attribute__((ext_vector_type(4)));

static __device__ __forceinline__ float sigmoidf_(float x) {
    return 1.0f / (1.0f + __expf(-x));
}
static __device__ __forceinline__ u16 f2b(float f) {   // RNE f32 -> bf16
    unsigned int u = __float_as_uint(f);
    u = (u + 0x7fffu + ((u >> 16) & 1u)) >> 16;
    return (u16)u;
}

// ----------------------------------------------------------------------------
// Straight cast f32 -> bf16, 8 elems/thread.
// ----------------------------------------------------------------------------
__global__ __launch_bounds__(256) void cast_bf16(
    const float* __restrict__ in, u16* __restrict__ out, int n8)
{
    const int i = blockIdx.x * 256 + threadIdx.x;
    if (i >= n8) return;
    const float4* p = reinterpret_cast<const float4*>(in + (size_t)i * 8);
    float4 v0 = p[0], v1 = p[1];
    union { u16 u[8]; uint4 q; } r;
    r.u[0] = f2b(v0.x); r.u[1] = f2b(v0.y); r.u[2] = f2b(v0.z); r.u[3] = f2b(v0.w);
    r.u[4] = f2b(v1.x); r.u[5] = f2b(v1.y); r.u[6] = f2b(v1.z); r.u[7] = f2b(v1.w);
    reinterpret_cast<uint4*>(out)[i] = r.q;
}

// ----------------------------------------------------------------------------
// Transpose-cast: in f32 [R][C] -> out bf16 [C][R]. 32x32 LDS tiles.
// ----------------------------------------------------------------------------
__global__ __launch_bounds__(256) void castT_bf16(
    const float* __restrict__ in, u16* __restrict__ out, int R, int C)
{
    __shared__ float t[32][33];
    const int r0 = blockIdx.y * 32, c0 = blockIdx.x * 32;
    const int tr = threadIdx.x >> 3;
    const int tc4 = (threadIdx.x & 7) * 4;
    const float4 v = *reinterpret_cast<const float4*>(in + (size_t)(r0 + tr) * C + c0 + tc4);
    t[tr][tc4 + 0] = v.x; t[tr][tc4 + 1] = v.y; t[tr][tc4 + 2] = v.z; t[tr][tc4 + 3] = v.w;
    __syncthreads();
    union { u16 u[4]; uint2 q; } r;
    #pragma unroll
    for (int j = 0; j < 4; j++) r.u[j] = f2b(t[tc4 + j][tr]);
    *reinterpret_cast<uint2*>(out + (size_t)(c0 + tr) * R + r0 + tc4) = r.q;
}

// ----------------------------------------------------------------------------
// bf16 MFMA GEMM (m97 structure): C_f32[M][N] = A[M][K] @ Bt[N][K]^T
// 128x128 tile, 4 waves (2x2 of 64x64), BK=32, 16x16x32 MFMA,
// global_load_lds width 16, 2 barriers per K-step.
// ----------------------------------------------------------------------------
__global__ __launch_bounds__(256) void gemm_bf16_tn(
    const u16* __restrict__ A, const u16* __restrict__ Bt,
    float* __restrict__ C, int M, int N, int K, int ldc)
{
    __shared__ u16 As[128 * 32];
    __shared__ u16 Bs[128 * 32];
    const int tid  = threadIdx.x;
    const int lane = tid & 63;
    const int wave = tid >> 6;
    const int wr = wave >> 1, wc = wave & 1;
    const int bm = blockIdx.y * 128, bn = blockIdx.x * 128;
    const int lhi = lane >> 4;      // 0..3 (k-slice)
    const int llo = lane & 15;      // row-within-fragment

    f32x4 acc[4][4] = {};

    for (int k0 = 0; k0 < K; k0 += 32) {
        #pragma unroll
        for (int c = 0; c < 2; ++c) {
            const int s   = c * 256 + wave * 64 + lane;
            const int row = s >> 2, seg = s & 3;
            const u16* ga = A  + (size_t)(bm + row) * K + k0 + seg * 8;
            const u16* gb = Bt + (size_t)(bn + row) * K + k0 + seg * 8;
            // LDS dest is wave-uniform base + lane*16 (linear layout == row*64B + seg*16B)
            __builtin_amdgcn_global_load_lds(
                (const __attribute__((address_space(1))) void*)ga,
                (__attribute__((address_space(3))) void*)(As + (size_t)(c * 256 + wave * 64) * 8),
                16, 0, 0);
            __builtin_amdgcn_global_load_lds(
                (const __attribute__((address_space(1))) void*)gb,
                (__attribute__((address_space(3))) void*)(Bs + (size_t)(c * 256 + wave * 64) * 8),
                16, 0, 0);
        }
        __syncthreads();   // drains vmcnt before any wave reads LDS

        bf16x8 af[4], bfr[4];
        #pragma unroll
        for (int m = 0; m < 4; ++m)
            af[m] = *reinterpret_cast<const bf16x8*>(&As[(wr * 64 + m * 16 + llo) * 32 + lhi * 8]);
        #pragma unroll
        for (int n = 0; n < 4; ++n)
            bfr[n] = *reinterpret_cast<const bf16x8*>(&Bs[(wc * 64 + n * 16 + llo) * 32 + lhi * 8]);
        #pragma unroll
        for (int m = 0; m < 4; ++m)
            #pragma unroll
            for (int n = 0; n < 4; ++n)
                acc[m][n] = __builtin_amdgcn_mfma_f32_16x16x32_bf16(af[m], bfr[n], acc[m][n], 0, 0, 0);
        __syncthreads();
    }

    // C/D layout: col = lane&15, row = (lane>>4)*4 + reg   [m89 verified]
    #pragma unroll
    for (int m = 0; m < 4; ++m) {
        const int row0 = bm + wr * 64 + m * 16 + lhi * 4;
        #pragma unroll
        for (int n = 0; n < 4; ++n) {
            const int col = bn + wc * 64 + n * 16 + llo;
            #pragma unroll
            for (int j = 0; j < 4; ++j)
                C[(size_t)(row0 + j) * ldc + col] = acc[m][n][j];
        }
    }
}

// ----------------------------------------------------------------------------
// Generic f32 tiled GEMM (kept for the two small GEMMs).
// epi==1: C = softplus(C + bias[col])
// ----------------------------------------------------------------------------
#define BM  64
#define BN  64
#define BKK 16

__global__ __launch_bounds__(256) void gemm_f32(
    const float* __restrict__ A, int lda,
    const float* __restrict__ B, int ldb,
    float* __restrict__ C, int ldc,
    int M, int N, int K, int epi, const float* __restrict__ bias)
{
    __shared__ float As[BKK][BM];
    __shared__ float Bs[BKK][BN];

    const int tid = threadIdx.x;
    const int bm = blockIdx.y * BM;
    const int bn = blockIdx.x * BN;
    const int tx = tid & 15;
    const int ty = tid >> 4;
    const int arow = tid >> 2;
    const int acol = (tid & 3) << 2;
    const int brow = tid >> 4;
    const int bcol = (tid & 15) << 2;

    float acc[4][4];
    #pragma unroll
    for (int i = 0; i < 4; i++)
        #pragma unroll
        for (int j = 0; j < 4; j++) acc[i][j] = 0.f;

    for (int k0 = 0; k0 < K; k0 += BKK) {
        float4 av = make_float4(0.f, 0.f, 0.f, 0.f);
        {
            const int gr = bm + arow;
            const int gc = k0 + acol;
            if (gr < M && gc + 4 <= K)
                av = *reinterpret_cast<const float4*>(A + (size_t)gr * lda + gc);
        }
        float4 bv = make_float4(0.f, 0.f, 0.f, 0.f);
        {
            const int gr = k0 + brow;
            const int gc = bn + bcol;
            if (gr < K && gc + 4 <= N)
                bv = *reinterpret_cast<const float4*>(B + (size_t)gr * ldb + gc);
        }
        As[acol + 0][arow] = av.x;
        As[acol + 1][arow] = av.y;
        As[acol + 2][arow] = av.z;
        As[acol + 3][arow] = av.w;
        *reinterpret_cast<float4*>(&Bs[brow][bcol]) = bv;
        __syncthreads();

        #pragma unroll
        for (int k = 0; k < BKK; k++) {
            float a[4], b[4];
            #pragma unroll
            for (int i = 0; i < 4; i++) a[i] = As[k][(ty << 2) + i];
            #pragma unroll
            for (int j = 0; j < 4; j++) b[j] = Bs[k][(tx << 2) + j];
            #pragma unroll
            for (int i = 0; i < 4; i++)
                #pragma unroll
                for (int j = 0; j < 4; j++)
                    acc[i][j] = fmaf(a[i], b[j], acc[i][j]);
        }
        __syncthreads();
    }

    #pragma unroll
    for (int i = 0; i < 4; i++) {
        const int row = bm + (ty << 2) + i;
        if (row >= M) continue;
        #pragma unroll
        for (int j = 0; j < 4; j++) {
            const int col = bn + (tx << 2) + j;
            if (col >= N) continue;
            float v = acc[i][j];
            if (epi == 1) {
                v += bias[col];
                v = (v > 20.f) ? v : log1pf(__expf(v));   // softplus
            }
            C[(size_t)row * ldc + col] = v;
        }
    }
}

// ----------------------------------------------------------------------------
// Causal depthwise conv (width 4, left pad 3) + bias + SiLU.
// ----------------------------------------------------------------------------
__global__ __launch_bounds__(256) void conv_silu(
    const float* __restrict__ xz, const float* __restrict__ conv_w,
    const float* __restrict__ conv_b, float* __restrict__ u)
{
    const int idx = blockIdx.x * 256 + threadIdx.x;
    if (idx >= B_SZ * LSEQ * DINNER) return;
    const int d  = idx & (DINNER - 1);
    const int bl = idx >> 11;
    const int l  = bl & (LSEQ - 1);

    float acc = conv_b[d];
    #pragma unroll
    for (int k = 0; k < DCONV; k++) {
        const int l2 = l - (DCONV - 1) + k;
        if (l2 >= 0) {
            acc = fmaf(xz[(size_t)(bl - (DCONV - 1) + k) * (2 * DINNER) + d],
                       conv_w[d * DCONV + k], acc);
        }
    }
    u[idx] = acc * sigmoidf_(acc);
}

// ----------------------------------------------------------------------------
// Chunk-parallel selective scan (3 phases).
// ----------------------------------------------------------------------------
__global__ __launch_bounds__(256) void scan_phase1(
    const float* __restrict__ delta, const float* __restrict__ u,
    const float* __restrict__ xdbl, const float* __restrict__ A_log,
    float* __restrict__ hend, float* __restrict__ Sd)
{
    const int idx = blockIdx.x * 256 + threadIdx.x;
    if (idx >= B_SZ * DINNER * NCHUNK) return;
    const int d = idx & (DINNER - 1);
    const int c = (idx >> 11) & (NCHUNK - 1);
    const int b = idx >> 17;

    float a[DSTATE];
    #pragma unroll
    for (int n = 0; n < DSTATE; n++) a[n] = -__expf(A_log[d * DSTATE + n]);

    float h[DSTATE];
    #pragma unroll
    for (int n = 0; n < DSTATE; n++) h[n] = 0.f;
    float sd = 0.f;

    const int l0 = b * LSEQ + c * CLEN;
    for (int i = 0; i < CLEN; ++i) {
        const size_t r = (size_t)(l0 + i);
        const float dv = delta[r * DINNER + d];
        const float uv = u[r * DINNER + d];
        sd += dv;
        const float4* bp = reinterpret_cast<const float4*>(xdbl + r * 96 + DTRANK);
        float Bv[DSTATE];
        {
            float4 t;
            t = bp[0]; Bv[0]=t.x; Bv[1]=t.y; Bv[2]=t.z;  Bv[3]=t.w;
            t = bp[1]; Bv[4]=t.x; Bv[5]=t.y; Bv[6]=t.z;  Bv[7]=t.w;
            t = bp[2]; Bv[8]=t.x; Bv[9]=t.y; Bv[10]=t.z; Bv[11]=t.w;
            t = bp[3]; Bv[12]=t.x; Bv[13]=t.y; Bv[14]=t.z; Bv[15]=t.w;
        }
        const float du = dv * uv;
        #pragma unroll
        for (int n = 0; n < DSTATE; n++)
            h[n] = fmaf(__expf(dv * a[n]), h[n], du * Bv[n]);
    }

    float* hp = hend + ((size_t)(b * DINNER + d) * NCHUNK + c) * DSTATE;
    #pragma unroll
    for (int n = 0; n < DSTATE; n += 4)
        *reinterpret_cast<float4*>(hp + n) = make_float4(h[n], h[n+1], h[n+2], h[n+3]);
    Sd[(size_t)(b * DINNER + d) * NCHUNK + c] = sd;
}

__global__ __launch_bounds__(256) void scan_phase2(
    float* __restrict__ hend, const float* __restrict__ Sd,
    const float* __restrict__ A_log)
{
    const int idx = blockIdx.x * 256 + threadIdx.x;
    if (idx >= B_SZ * DINNER * DSTATE) return;
    const int n = idx & (DSTATE - 1);
    const int d = (idx >> 4) & (DINNER - 1);
    const int b = idx >> 15;

    const float an = -__expf(A_log[d * DSTATE + n]);
    const size_t base = (size_t)(b * DINNER + d) * NCHUNK;
    float carry = 0.f;
    for (int c = 0; c < NCHUNK; ++c) {
        const float P = __expf(an * Sd[base + c]);
        const size_t off = (base + c) * DSTATE + n;
        const float tmp = hend[off];
        hend[off] = carry;
        carry = fmaf(P, carry, tmp);
    }
}

__global__ __launch_bounds__(256) void scan_phase3(
    const float* __restrict__ dy /* delta */,
    const float* __restrict__ u, const float* __restrict__ xdbl,
    const float* __restrict__ xz, const float* __restrict__ A_log,
    const float* __restrict__ Dp, const float* __restrict__ hin,
    u16* __restrict__ ybf)
{
    const int idx = blockIdx.x * 256 + threadIdx.x;
    if (idx >= B_SZ * DINNER * NCHUNK) return;
    const int d = idx & (DINNER - 1);
    const int c = (idx >> 11) & (NCHUNK - 1);
    const int b = idx >> 17;

    float a[DSTATE];
    #pragma unroll
    for (int n = 0; n < DSTATE; n++) a[n] = -__expf(A_log[d * DSTATE + n]);
    const float Dd = Dp[d];

    float h[DSTATE];
    {
        const float* hp = hin + ((size_t)(b * DINNER + d) * NCHUNK + c) * DSTATE;
        #pragma unroll
        for (int n = 0; n < DSTATE; n += 4) {
            float4 t = *reinterpret_cast<const float4*>(hp + n);
            h[n] = t.x; h[n+1] = t.y; h[n+2] = t.z; h[n+3] = t.w;
        }
    }

    const int l0 = b * LSEQ + c * CLEN;
    for (int i = 0; i < CLEN; ++i) {
        const size_t r = (size_t)(l0 + i);
        const float dv = dy[r * DINNER + d];
        const float uv = u[r * DINNER + d];

        const float4* bp = reinterpret_cast<const float4*>(xdbl + r * 96 + DTRANK);
        float Bv[DSTATE], Cv[DSTATE];
        {
            float4 t;
            t = bp[0]; Bv[0]=t.x; Bv[1]=t.y; Bv[2]=t.z;  Bv[3]=t.w;
            t = bp[1]; Bv[4]=t.x; Bv[5]=t.y; Bv[6]=t.z;  Bv[7]=t.w;
            t = bp[2]; Bv[8]=t.x; Bv[9]=t.y; Bv[10]=t.z; Bv[11]=t.w;
            t = bp[3]; Bv[12]=t.x; Bv[13]=t.y; Bv[14]=t.z; Bv[15]=t.w;
            t = bp[4]; Cv[0]=t.x; Cv[1]=t.y; Cv[2]=t.z;  Cv[3]=t.w;
            t = bp[5]; Cv[4]=t.x; Cv[5]=t.y; Cv[6]=t.z;  Cv[7]=t.w;
            t = bp[6]; Cv[8]=t.x; Cv[9]=t.y; Cv[10]=t.z; Cv[11]=t.w;
            t = bp[7]; Cv[12]=t.x; Cv[13]=t.y; Cv[14]=t.z; Cv[15]=t.w;
        }

        const float du = dv * uv;
        float yv = 0.f;
        #pragma unroll
        for (int n = 0; n < DSTATE; n++) {
            h[n] = fmaf(__expf(dv * a[n]), h[n], du * Bv[n]);
            yv = fmaf(h[n], Cv[n], yv);
        }
        yv = fmaf(uv, Dd, yv);

        const float rv = xz[r * (2 * DINNER) + DINNER + d];
        ybf[r * DINNER + d] = f2b(yv * (rv * sigmoidf_(rv)));
    }
}

// ----------------------------------------------------------------------------
extern "C" void kernel_launch(void* const* d_in, const int* in_sizes, int n_in,
                              void* d_out, int out_size, void* d_ws, size_t ws_size,
                              hipStream_t stream) {
    const float* x      = (const float*)d_in[0];
    const float* W_in   = (const float*)d_in[1];
    const float* conv_w = (const float*)d_in[2];
    const float* conv_b = (const float*)d_in[3];
    const float* W_x    = (const float*)d_in[4];
    const float* W_dt   = (const float*)d_in[5];
    const float* b_dt   = (const float*)d_in[6];
    const float* A_log  = (const float*)d_in[7];
    const float* Dp     = (const float*)d_in[8];
    const float* W_out  = (const float*)d_in[9];
    float* out = (float*)d_out;

    float* ws   = (float*)d_ws;
    float* xz   = ws;                                   // [4096,4096] f32 (64MB)
    float* u    = xz   + (size_t)4096 * 4096;           // [4096,2048] f32
    float* xdbl = u    + (size_t)4096 * 2048;           // [4096,96]   f32
    float* dy   = xdbl + (size_t)4096 * 96;             // [4096,2048] delta f32
    float* hend = dy   + (size_t)4096 * 2048;           // [2,2048,NCHUNK,16]
    float* Sd   = hend + (size_t)B_SZ * DINNER * NCHUNK * DSTATE;  // [2,2048,NCHUNK]
    u16*   bfp  = (u16*)(Sd + (size_t)B_SZ * DINNER * NCHUNK);
    u16*   xbf  = bfp;                                  // [4096,1024] bf16 (8MB)
    u16*   WinT = xbf + (size_t)4096 * 1024;            // [4096,1024] bf16 (W_in^T)
    u16*   ybf  = xbf;                                  // [4096,2048] bf16, aliases xbf+WinT (dead after GEMM1)
    u16*   WoutT = (u16*)xz;                            // [1024,2048] bf16, aliases xz (dead after phase3)

    const int M = B_SZ * LSEQ;   // 4096
    dim3 blk(256);

    // 0) casts for GEMM1
    cast_bf16<<<dim3((M * DMODEL / 8) / 256), blk, 0, stream>>>(x, xbf, M * DMODEL / 8);
    castT_bf16<<<dim3((2 * DINNER) / 32, DMODEL / 32), blk, 0, stream>>>(
        W_in, WinT, DMODEL, 2 * DINNER);

    // 1) xz = x @ W_in   (bf16 MFMA)  [4096,1024]x[1024,4096]
    gemm_bf16_tn<<<dim3((2 * DINNER) / 128, M / 128), blk, 0, stream>>>(
        xbf, WinT, xz, M, 2 * DINNER, DMODEL, 2 * DINNER);

    // 2) u = silu(causal_conv(xs) + conv_b)
    conv_silu<<<dim3((M * DINNER) / 256), blk, 0, stream>>>(xz, conv_w, conv_b, u);

    // 3) xdbl = u @ W_x   (f32)       [4096,2048]x[2048,96]
    gemm_f32<<<dim3((96 + BN - 1) / BN, M / BM), blk, 0, stream>>>(
        u, DINNER, W_x, 96, xdbl, 96, M, 96, DINNER, 0, nullptr);

    // 4) delta = softplus(xdbl[:, :64] @ W_dt + b_dt)  (f32)
    gemm_f32<<<dim3(DINNER / BN, M / BM), blk, 0, stream>>>(
        xdbl, 96, W_dt, DINNER, dy, DINNER, M, DINNER, DTRANK, 1, b_dt);

    // 5) chunk-parallel scan; phase3 emits y directly as bf16
    scan_phase1<<<dim3((B_SZ * DINNER * NCHUNK) / 256), blk, 0, stream>>>(
        dy, u, xdbl, A_log, hend, Sd);
    scan_phase2<<<dim3((B_SZ * DINNER * DSTATE) / 256), blk, 0, stream>>>(
        hend, Sd, A_log);
    scan_phase3<<<dim3((B_SZ * DINNER * NCHUNK) / 256), blk, 0, stream>>>(
        dy, u, xdbl, xz, A_log, Dp, hend, ybf);

    // 5b) W_out^T cast (into dead xz region)
    castT_bf16<<<dim3(DMODEL / 32, DINNER / 32), blk, 0, stream>>>(
        W_out, WoutT, DINNER, DMODEL);

    // 6) out = y @ W_out  (bf16 MFMA)  [4096,2048]x[2048,1024]
    gemm_bf16_tn<<<dim3(DMODEL / 128, M / 128), blk, 0, stream>>>(
        ybf, WoutT, out, M, DMODEL, DINNER, DMODEL);
}

// Round 5
// 420.474 us; speedup vs baseline: 5.9044x; 1.2473x over previous
//
#include <hip/hip_runtime.h>
#include <hip/hip_bf16.h>
#include <math.h>

#define B_SZ    2
#define LSEQ    2048
#define DMODEL  1024
#define DINNER  2048
#define DSTATE  16
#define DCONV   4
#define DTRANK  64

#define NCHUNK  64
#define CLEN    (LSEQ / NCHUNK)   // 32

#define KSPLIT  16                // GEMM3 split-K factor (K-chunk = 128)
#define NX      96                // DT_RANK + 2*DSTATE

typedef unsigned short u16;
typedef __bf16 bf16x8 __attribute__((ext_vector_type(8)));
typedef float  f32x4  __attribute__((ext_vector_type(4)));

static __device__ __forceinline__ float sigmoidf_(float x) {
    return 1.0f / (1.0f + __expf(-x));
}
static __device__ __forceinline__ u16 f2b(float f) {   // RNE f32 -> bf16
    unsigned int u = __float_as_uint(f);
    u = (u + 0x7fffu + ((u >> 16) & 1u)) >> 16;
    return (u16)u;
}

// ----------------------------------------------------------------------------
// Straight cast f32 -> bf16, 8 elems/thread.
// ----------------------------------------------------------------------------
__global__ __launch_bounds__(256) void cast_bf16(
    const float* __restrict__ in, u16* __restrict__ out, int n8)
{
    const int i = blockIdx.x * 256 + threadIdx.x;
    if (i >= n8) return;
    const float4* p = reinterpret_cast<const float4*>(in + (size_t)i * 8);
    float4 v0 = p[0], v1 = p[1];
    union { u16 u[8]; uint4 q; } r;
    r.u[0] = f2b(v0.x); r.u[1] = f2b(v0.y); r.u[2] = f2b(v0.z); r.u[3] = f2b(v0.w);
    r.u[4] = f2b(v1.x); r.u[5] = f2b(v1.y); r.u[6] = f2b(v1.z); r.u[7] = f2b(v1.w);
    reinterpret_cast<uint4*>(out)[i] = r.q;
}

// ----------------------------------------------------------------------------
// Transpose-cast: in f32 [R][C] -> out bf16 [C][R]. 32x32 LDS tiles.
// ----------------------------------------------------------------------------
__global__ __launch_bounds__(256) void castT_bf16(
    const float* __restrict__ in, u16* __restrict__ out, int R, int C)
{
    __shared__ float t[32][33];
    const int r0 = blockIdx.y * 32, c0 = blockIdx.x * 32;
    const int tr = threadIdx.x >> 3;
    const int tc4 = (threadIdx.x & 7) * 4;
    const float4 v = *reinterpret_cast<const float4*>(in + (size_t)(r0 + tr) * C + c0 + tc4);
    t[tr][tc4 + 0] = v.x; t[tr][tc4 + 1] = v.y; t[tr][tc4 + 2] = v.z; t[tr][tc4 + 3] = v.w;
    __syncthreads();
    union { u16 u[4]; uint2 q; } r;
    #pragma unroll
    for (int j = 0; j < 4; j++) r.u[j] = f2b(t[tc4 + j][tr]);
    *reinterpret_cast<uint2*>(out + (size_t)(c0 + tr) * R + r0 + tc4) = r.q;
}

// ----------------------------------------------------------------------------
// bf16 MFMA GEMM (m97 structure): C_f32[M][N] = A[M][K] @ Bt[N][K]^T
// ----------------------------------------------------------------------------
__global__ __launch_bounds__(256) void gemm_bf16_tn(
    const u16* __restrict__ A, const u16* __restrict__ Bt,
    float* __restrict__ C, int M, int N, int K, int ldc)
{
    __shared__ u16 As[128 * 32];
    __shared__ u16 Bs[128 * 32];
    const int tid  = threadIdx.x;
    const int lane = tid & 63;
    const int wave = tid >> 6;
    const int wr = wave >> 1, wc = wave & 1;
    const int bm = blockIdx.y * 128, bn = blockIdx.x * 128;
    const int lhi = lane >> 4;
    const int llo = lane & 15;

    f32x4 acc[4][4] = {};

    for (int k0 = 0; k0 < K; k0 += 32) {
        #pragma unroll
        for (int c = 0; c < 2; ++c) {
            const int s   = c * 256 + wave * 64 + lane;
            const int row = s >> 2, seg = s & 3;
            const u16* ga = A  + (size_t)(bm + row) * K + k0 + seg * 8;
            const u16* gb = Bt + (size_t)(bn + row) * K + k0 + seg * 8;
            __builtin_amdgcn_global_load_lds(
                (const __attribute__((address_space(1))) void*)ga,
                (__attribute__((address_space(3))) void*)(As + (size_t)(c * 256 + wave * 64) * 8),
                16, 0, 0);
            __builtin_amdgcn_global_load_lds(
                (const __attribute__((address_space(1))) void*)gb,
                (__attribute__((address_space(3))) void*)(Bs + (size_t)(c * 256 + wave * 64) * 8),
                16, 0, 0);
        }
        __syncthreads();

        bf16x8 af[4], bfr[4];
        #pragma unroll
        for (int m = 0; m < 4; ++m)
            af[m] = *reinterpret_cast<const bf16x8*>(&As[(wr * 64 + m * 16 + llo) * 32 + lhi * 8]);
        #pragma unroll
        for (int n = 0; n < 4; ++n)
            bfr[n] = *reinterpret_cast<const bf16x8*>(&Bs[(wc * 64 + n * 16 + llo) * 32 + lhi * 8]);
        #pragma unroll
        for (int m = 0; m < 4; ++m)
            #pragma unroll
            for (int n = 0; n < 4; ++n)
                acc[m][n] = __builtin_amdgcn_mfma_f32_16x16x32_bf16(af[m], bfr[n], acc[m][n], 0, 0, 0);
        __syncthreads();
    }

    #pragma unroll
    for (int m = 0; m < 4; ++m) {
        const int row0 = bm + wr * 64 + m * 16 + lhi * 4;
        #pragma unroll
        for (int n = 0; n < 4; ++n) {
            const int col = bn + wc * 64 + n * 16 + llo;
            #pragma unroll
            for (int j = 0; j < 4; ++j)
                C[(size_t)(row0 + j) * ldc + col] = acc[m][n][j];
        }
    }
}

// ----------------------------------------------------------------------------
// GEMM3 split-K: partial[s][M][96] = u[M, s*128:(s+1)*128] @ W_x[s*128:(s+1)*128, :96]
// grid = (M/64, KSPLIT). Block: 64 rows x 96 cols, 24 acc/thread.
// ----------------------------------------------------------------------------
__global__ __launch_bounds__(256) void gemm3_splitk(
    const float* __restrict__ u, const float* __restrict__ Wx,
    float* __restrict__ partial)
{
    __shared__ float us[64][65];     // +1 pad: kills 16-way conflict on u_s[r][kk]
    __shared__ float wsm[64][96];

    const int tid = threadIdx.x;
    const int r0 = blockIdx.x * 64;
    const int k0 = blockIdx.y * (DINNER / KSPLIT);   // 128-wide K slice

    const int orow = tid >> 2;            // 0..63 output row
    const int oc0  = (tid & 3) * 24;      // output col group

    float acc[24];
    #pragma unroll
    for (int j = 0; j < 24; j++) acc[j] = 0.f;

    for (int ks = 0; ks < DINNER / KSPLIT; ks += 64) {
        // stage u[64][64]
        #pragma unroll
        for (int i = 0; i < 4; i++) {
            const int row = (tid >> 4) + i * 16;
            const int kc4 = (tid & 15) * 4;
            const float4 v = *reinterpret_cast<const float4*>(
                u + (size_t)(r0 + row) * DINNER + k0 + ks + kc4);
            us[row][kc4] = v.x; us[row][kc4+1] = v.y; us[row][kc4+2] = v.z; us[row][kc4+3] = v.w;
        }
        // stage W_x[64][96]
        #pragma unroll
        for (int j = 0; j < 6; j++) {
            const int fid = tid + j * 256;        // 0..1535
            const int kr  = fid / 24;
            const int c4  = (fid % 24) * 4;
            *reinterpret_cast<float4*>(&wsm[kr][c4]) =
                *reinterpret_cast<const float4*>(Wx + (size_t)(k0 + ks + kr) * NX + c4);
        }
        __syncthreads();

        for (int kk = 0; kk < 64; ++kk) {
            const float uv = us[orow][kk];
            #pragma unroll
            for (int j = 0; j < 24; j++)
                acc[j] = fmaf(uv, wsm[kk][oc0 + j], acc[j]);
        }
        __syncthreads();
    }

    float* pp = partial + ((size_t)blockIdx.y * (B_SZ * LSEQ) + r0 + orow) * NX + oc0;
    #pragma unroll
    for (int j = 0; j < 24; j += 4)
        *reinterpret_cast<float4*>(pp + j) = make_float4(acc[j], acc[j+1], acc[j+2], acc[j+3]);
}

__global__ __launch_bounds__(256) void gemm3_reduce(
    const float* __restrict__ partial, float* __restrict__ xdbl)
{
    const int i = blockIdx.x * 256 + threadIdx.x;   // float4 index over [M][96]
    if (i >= B_SZ * LSEQ * NX / 4) return;
    float4 s = make_float4(0.f, 0.f, 0.f, 0.f);
    #pragma unroll
    for (int p = 0; p < KSPLIT; p++) {
        const float4 v = reinterpret_cast<const float4*>(
            partial + (size_t)p * (B_SZ * LSEQ) * NX)[i];
        s.x += v.x; s.y += v.y; s.z += v.z; s.w += v.w;
    }
    reinterpret_cast<float4*>(xdbl)[i] = s;
}

// ----------------------------------------------------------------------------
// Generic f32 tiled GEMM (kept for GEMM4). epi==1: softplus(C + bias[col])
// ----------------------------------------------------------------------------
#define BM  64
#define BN  64
#define BKK 16

__global__ __launch_bounds__(256) void gemm_f32(
    const float* __restrict__ A, int lda,
    const float* __restrict__ B, int ldb,
    float* __restrict__ C, int ldc,
    int M, int N, int K, int epi, const float* __restrict__ bias)
{
    __shared__ float As[BKK][BM];
    __shared__ float Bs[BKK][BN];

    const int tid = threadIdx.x;
    const int bm = blockIdx.y * BM;
    const int bn = blockIdx.x * BN;
    const int tx = tid & 15;
    const int ty = tid >> 4;
    const int arow = tid >> 2;
    const int acol = (tid & 3) << 2;
    const int brow = tid >> 4;
    const int bcol = (tid & 15) << 2;

    float acc[4][4];
    #pragma unroll
    for (int i = 0; i < 4; i++)
        #pragma unroll
        for (int j = 0; j < 4; j++) acc[i][j] = 0.f;

    for (int k0 = 0; k0 < K; k0 += BKK) {
        float4 av = make_float4(0.f, 0.f, 0.f, 0.f);
        {
            const int gr = bm + arow;
            const int gc = k0 + acol;
            if (gr < M && gc + 4 <= K)
                av = *reinterpret_cast<const float4*>(A + (size_t)gr * lda + gc);
        }
        float4 bv = make_float4(0.f, 0.f, 0.f, 0.f);
        {
            const int gr = k0 + brow;
            const int gc = bn + bcol;
            if (gr < K && gc + 4 <= N)
                bv = *reinterpret_cast<const float4*>(B + (size_t)gr * ldb + gc);
        }
        As[acol + 0][arow] = av.x;
        As[acol + 1][arow] = av.y;
        As[acol + 2][arow] = av.z;
        As[acol + 3][arow] = av.w;
        *reinterpret_cast<float4*>(&Bs[brow][bcol]) = bv;
        __syncthreads();

        #pragma unroll
        for (int k = 0; k < BKK; k++) {
            float a[4], b[4];
            #pragma unroll
            for (int i = 0; i < 4; i++) a[i] = As[k][(ty << 2) + i];
            #pragma unroll
            for (int j = 0; j < 4; j++) b[j] = Bs[k][(tx << 2) + j];
            #pragma unroll
            for (int i = 0; i < 4; i++)
                #pragma unroll
                for (int j = 0; j < 4; j++)
                    acc[i][j] = fmaf(a[i], b[j], acc[i][j]);
        }
        __syncthreads();
    }

    #pragma unroll
    for (int i = 0; i < 4; i++) {
        const int row = bm + (ty << 2) + i;
        if (row >= M) continue;
        #pragma unroll
        for (int j = 0; j < 4; j++) {
            const int col = bn + (tx << 2) + j;
            if (col >= N) continue;
            float v = acc[i][j];
            if (epi == 1) {
                v += bias[col];
                v = (v > 20.f) ? v : log1pf(__expf(v));   // softplus
            }
            C[(size_t)row * ldc + col] = v;
        }
    }
}

// ----------------------------------------------------------------------------
// Causal depthwise conv (width 4, left pad 3) + bias + SiLU.
// ----------------------------------------------------------------------------
__global__ __launch_bounds__(256) void conv_silu(
    const float* __restrict__ xz, const float* __restrict__ conv_w,
    const float* __restrict__ conv_b, float* __restrict__ u)
{
    const int idx = blockIdx.x * 256 + threadIdx.x;
    if (idx >= B_SZ * LSEQ * DINNER) return;
    const int d  = idx & (DINNER - 1);
    const int bl = idx >> 11;
    const int l  = bl & (LSEQ - 1);

    float acc = conv_b[d];
    #pragma unroll
    for (int k = 0; k < DCONV; k++) {
        const int l2 = l - (DCONV - 1) + k;
        if (l2 >= 0) {
            acc = fmaf(xz[(size_t)(bl - (DCONV - 1) + k) * (2 * DINNER) + d],
                       conv_w[d * DCONV + k], acc);
        }
    }
    u[idx] = acc * sigmoidf_(acc);
}

// ----------------------------------------------------------------------------
// Chunk-parallel selective scan (3 phases).
// ----------------------------------------------------------------------------
__global__ __launch_bounds__(256) void scan_phase1(
    const float* __restrict__ delta, const float* __restrict__ u,
    const float* __restrict__ xdbl, const float* __restrict__ A_log,
    float* __restrict__ hend, float* __restrict__ Sd)
{
    const int idx = blockIdx.x * 256 + threadIdx.x;
    if (idx >= B_SZ * DINNER * NCHUNK) return;
    const int d = idx & (DINNER - 1);
    const int c = (idx >> 11) & (NCHUNK - 1);
    const int b = idx >> 17;

    float a[DSTATE];
    #pragma unroll
    for (int n = 0; n < DSTATE; n++) a[n] = -__expf(A_log[d * DSTATE + n]);

    float h[DSTATE];
    #pragma unroll
    for (int n = 0; n < DSTATE; n++) h[n] = 0.f;
    float sd = 0.f;

    const int l0 = b * LSEQ + c * CLEN;
    for (int i = 0; i < CLEN; ++i) {
        const size_t r = (size_t)(l0 + i);
        const float dv = delta[r * DINNER + d];
        const float uv = u[r * DINNER + d];
        sd += dv;
        const float4* bp = reinterpret_cast<const float4*>(xdbl + r * NX + DTRANK);
        float Bv[DSTATE];
        {
            float4 t;
            t = bp[0]; Bv[0]=t.x; Bv[1]=t.y; Bv[2]=t.z;  Bv[3]=t.w;
            t = bp[1]; Bv[4]=t.x; Bv[5]=t.y; Bv[6]=t.z;  Bv[7]=t.w;
            t = bp[2]; Bv[8]=t.x; Bv[9]=t.y; Bv[10]=t.z; Bv[11]=t.w;
            t = bp[3]; Bv[12]=t.x; Bv[13]=t.y; Bv[14]=t.z; Bv[15]=t.w;
        }
        const float du = dv * uv;
        #pragma unroll
        for (int n = 0; n < DSTATE; n++)
            h[n] = fmaf(__expf(dv * a[n]), h[n], du * Bv[n]);
    }

    float* hp = hend + ((size_t)(b * DINNER + d) * NCHUNK + c) * DSTATE;
    #pragma unroll
    for (int n = 0; n < DSTATE; n += 4)
        *reinterpret_cast<float4*>(hp + n) = make_float4(h[n], h[n+1], h[n+2], h[n+3]);
    Sd[(size_t)(b * DINNER + d) * NCHUNK + c] = sd;
}

__global__ __launch_bounds__(256) void scan_phase2(
    float* __restrict__ hend, const float* __restrict__ Sd,
    const float* __restrict__ A_log)
{
    const int idx = blockIdx.x * 256 + threadIdx.x;
    if (idx >= B_SZ * DINNER * DSTATE) return;
    const int n = idx & (DSTATE - 1);
    const int d = (idx >> 4) & (DINNER - 1);
    const int b = idx >> 15;

    const float an = -__expf(A_log[d * DSTATE + n]);
    const size_t base = (size_t)(b * DINNER + d) * NCHUNK;
    float carry = 0.f;
    for (int c = 0; c < NCHUNK; ++c) {
        const float P = __expf(an * Sd[base + c]);
        const size_t off = (base + c) * DSTATE + n;
        const float tmp = hend[off];
        hend[off] = carry;
        carry = fmaf(P, carry, tmp);
    }
}

__global__ __launch_bounds__(256) void scan_phase3(
    const float* __restrict__ dy /* delta */,
    const float* __restrict__ u, const float* __restrict__ xdbl,
    const float* __restrict__ xz, const float* __restrict__ A_log,
    const float* __restrict__ Dp, const float* __restrict__ hin,
    u16* __restrict__ ybf)
{
    const int idx = blockIdx.x * 256 + threadIdx.x;
    if (idx >= B_SZ * DINNER * NCHUNK) return;
    const int d = idx & (DINNER - 1);
    const int c = (idx >> 11) & (NCHUNK - 1);
    const int b = idx >> 17;

    float a[DSTATE];
    #pragma unroll
    for (int n = 0; n < DSTATE; n++) a[n] = -__expf(A_log[d * DSTATE + n]);
    const float Dd = Dp[d];

    float h[DSTATE];
    {
        const float* hp = hin + ((size_t)(b * DINNER + d) * NCHUNK + c) * DSTATE;
        #pragma unroll
        for (int n = 0; n < DSTATE; n += 4) {
            float4 t = *reinterpret_cast<const float4*>(hp + n);
            h[n] = t.x; h[n+1] = t.y; h[n+2] = t.z; h[n+3] = t.w;
        }
    }

    const int l0 = b * LSEQ + c * CLEN;
    for (int i = 0; i < CLEN; ++i) {
        const size_t r = (size_t)(l0 + i);
        const float dv = dy[r * DINNER + d];
        const float uv = u[r * DINNER + d];

        const float4* bp = reinterpret_cast<const float4*>(xdbl + r * NX + DTRANK);
        float Bv[DSTATE], Cv[DSTATE];
        {
            float4 t;
            t = bp[0]; Bv[0]=t.x; Bv[1]=t.y; Bv[2]=t.z;  Bv[3]=t.w;
            t = bp[1]; Bv[4]=t.x; Bv[5]=t.y; Bv[6]=t.z;  Bv[7]=t.w;
            t = bp[2]; Bv[8]=t.x; Bv[9]=t.y; Bv[10]=t.z; Bv[11]=t.w;
            t = bp[3]; Bv[12]=t.x; Bv[13]=t.y; Bv[14]=t.z; Bv[15]=t.w;
            t = bp[4]; Cv[0]=t.x; Cv[1]=t.y; Cv[2]=t.z;  Cv[3]=t.w;
            t = bp[5]; Cv[4]=t.x; Cv[5]=t.y; Cv[6]=t.z;  Cv[7]=t.w;
            t = bp[6]; Cv[8]=t.x; Cv[9]=t.y; Cv[10]=t.z; Cv[11]=t.w;
            t = bp[7]; Cv[12]=t.x; Cv[13]=t.y; Cv[14]=t.z; Cv[15]=t.w;
        }

        const float du = dv * uv;
        float yv = 0.f;
        #pragma unroll
        for (int n = 0; n < DSTATE; n++) {
            h[n] = fmaf(__expf(dv * a[n]), h[n], du * Bv[n]);
            yv = fmaf(h[n], Cv[n], yv);
        }
        yv = fmaf(uv, Dd, yv);

        const float rv = xz[r * (2 * DINNER) + DINNER + d];
        ybf[r * DINNER + d] = f2b(yv * (rv * sigmoidf_(rv)));
    }
}

// ----------------------------------------------------------------------------
extern "C" void kernel_launch(void* const* d_in, const int* in_sizes, int n_in,
                              void* d_out, int out_size, void* d_ws, size_t ws_size,
                              hipStream_t stream) {
    const float* x      = (const float*)d_in[0];
    const float* W_in   = (const float*)d_in[1];
    const float* conv_w = (const float*)d_in[2];
    const float* conv_b = (const float*)d_in[3];
    const float* W_x    = (const float*)d_in[4];
    const float* W_dt   = (const float*)d_in[5];
    const float* b_dt   = (const float*)d_in[6];
    const float* A_log  = (const float*)d_in[7];
    const float* Dp     = (const float*)d_in[8];
    const float* W_out  = (const float*)d_in[9];
    float* out = (float*)d_out;

    float* ws   = (float*)d_ws;
    float* xz   = ws;                                   // [4096,4096] f32 (64MB)
    float* u    = xz   + (size_t)4096 * 4096;           // [4096,2048] f32
    float* xdbl = u    + (size_t)4096 * 2048;           // [4096,96]   f32
    float* dy   = xdbl + (size_t)4096 * 96;             // [4096,2048] delta f32
    float* hend = dy   + (size_t)4096 * 2048;           // [2,2048,NCHUNK,16]
    float* Sd   = hend + (size_t)B_SZ * DINNER * NCHUNK * DSTATE;  // [2,2048,NCHUNK]
    u16*   bfp  = (u16*)(Sd + (size_t)B_SZ * DINNER * NCHUNK);
    u16*   xbf  = bfp;                                  // [4096,1024] bf16 (8MB)
    u16*   WinT = xbf + (size_t)4096 * 1024;            // [4096,1024] bf16 (W_in^T)
    u16*   ybf  = xbf;                                  // [4096,2048] bf16, aliases xbf+WinT
    u16*   WoutT = (u16*)xz;                            // [1024,2048] bf16, aliases xz (dead after phase3)
    float* part = dy;                                   // [KSPLIT,4096,96] 25MB, aliases dy (dead until GEMM4)

    const int M = B_SZ * LSEQ;   // 4096
    dim3 blk(256);

    // 0) casts for GEMM1
    cast_bf16<<<dim3((M * DMODEL / 8) / 256), blk, 0, stream>>>(x, xbf, M * DMODEL / 8);
    castT_bf16<<<dim3((2 * DINNER) / 32, DMODEL / 32), blk, 0, stream>>>(
        W_in, WinT, DMODEL, 2 * DINNER);

    // 1) xz = x @ W_in   (bf16 MFMA)  [4096,1024]x[1024,4096]
    gemm_bf16_tn<<<dim3((2 * DINNER) / 128, M / 128), blk, 0, stream>>>(
        xbf, WinT, xz, M, 2 * DINNER, DMODEL, 2 * DINNER);

    // 2) u = silu(causal_conv(xs) + conv_b)
    conv_silu<<<dim3((M * DINNER) / 256), blk, 0, stream>>>(xz, conv_w, conv_b, u);

    // 3) xdbl = u @ W_x   (split-K f32)   [4096,2048]x[2048,96]
    gemm3_splitk<<<dim3(M / 64, KSPLIT), blk, 0, stream>>>(u, W_x, part);
    gemm3_reduce<<<dim3((M * NX / 4 + 255) / 256), blk, 0, stream>>>(part, xdbl);

    // 4) delta = softplus(xdbl[:, :64] @ W_dt + b_dt)  (f32)  [4096,64]x[64,2048]
    gemm_f32<<<dim3(DINNER / BN, M / BM), blk, 0, stream>>>(
        xdbl, NX, W_dt, DINNER, dy, DINNER, M, DINNER, DTRANK, 1, b_dt);

    // 5) chunk-parallel scan; phase3 emits y directly as bf16
    scan_phase1<<<dim3((B_SZ * DINNER * NCHUNK) / 256), blk, 0, stream>>>(
        dy, u, xdbl, A_log, hend, Sd);
    scan_phase2<<<dim3((B_SZ * DINNER * DSTATE) / 256), blk, 0, stream>>>(
        hend, Sd, A_log);
    scan_phase3<<<dim3((B_SZ * DINNER * NCHUNK) / 256), blk, 0, stream>>>(
        dy, u, xdbl, xz, A_log, Dp, hend, ybf);

    // 5b) W_out^T cast (into dead xz region)
    castT_bf16<<<dim3(DMODEL / 32, DINNER / 32), blk, 0, stream>>>(
        W_out, WoutT, DINNER, DMODEL);

    // 6) out = y @ W_out  (bf16 MFMA)  [4096,2048]x[2048,1024]
    gemm_bf16_tn<<<dim3(DMODEL / 128, M / 128), blk, 0, stream>>>(
        ybf, WoutT, out, M, DMODEL, DINNER, DMODEL);
}